// Round 1
// baseline (91.168 us; speedup 1.0000x reference)
//
#include <hip/hip_runtime.h>

#define BB 32
#define SS 4096
#define DD 256

// ---------------------------------------------------------------------------
// Kernel 1: A1[b,s] = dot(wd[b,s,:], e1[b,:]); A2 likewise.
// One wave (64 lanes) per (b,s) row; lane i handles float4 at d = 4*i.
// ---------------------------------------------------------------------------
__global__ __launch_bounds__(256) void dots_kernel(const float* __restrict__ wd,
                                                   const float* __restrict__ e1,
                                                   const float* __restrict__ e2,
                                                   float* __restrict__ A1,
                                                   float* __restrict__ A2) {
    const int wave = (int)((blockIdx.x * blockDim.x + threadIdx.x) >> 6);
    const int lane = threadIdx.x & 63;
    const int b = wave / SS;

    const float4* wdv = reinterpret_cast<const float4*>(wd + (size_t)wave * DD);
    const float4* e1v = reinterpret_cast<const float4*>(e1 + b * DD);
    const float4* e2v = reinterpret_cast<const float4*>(e2 + b * DD);

    float4 w  = wdv[lane];
    float4 x1 = e1v[lane];
    float4 x2 = e2v[lane];

    float d1 = w.x * x1.x + w.y * x1.y + w.z * x1.z + w.w * x1.w;
    float d2 = w.x * x2.x + w.y * x2.y + w.z * x2.z + w.w * x2.w;

    #pragma unroll
    for (int m = 32; m >= 1; m >>= 1) {
        d1 += __shfl_xor(d1, m, 64);
        d2 += __shfl_xor(d2, m, 64);
    }
    if (lane == 0) {
        A1[wave] = d1;
        A2[wave] = d2;
    }
}

// ---------------------------------------------------------------------------
// Kernel 2: per-b softmax stats. One block (256 threads) per b.
// stats[b] = {m1, 1/l1, m2, 1/l2}
// ---------------------------------------------------------------------------
__global__ __launch_bounds__(256) void stats_kernel(const float* __restrict__ A1,
                                                    const float* __restrict__ A2,
                                                    float* __restrict__ stats) {
    const int b = blockIdx.x;
    const int t = threadIdx.x;
    __shared__ float red[256];

    const float* A[2] = {A1 + (size_t)b * SS, A2 + (size_t)b * SS};
    float res[4];

    #pragma unroll
    for (int k = 0; k < 2; ++k) {
        // --- max ---
        float m = -3.0e38f;
        for (int i = t; i < SS; i += 256) m = fmaxf(m, A[k][i]);
        red[t] = m;
        __syncthreads();
        for (int off = 128; off >= 1; off >>= 1) {
            if (t < off) red[t] = fmaxf(red[t], red[t + off]);
            __syncthreads();
        }
        m = red[0];
        __syncthreads();
        // --- sum of exp ---
        float sum = 0.0f;
        for (int i = t; i < SS; i += 256) sum += __expf(A[k][i] - m);
        red[t] = sum;
        __syncthreads();
        for (int off = 128; off >= 1; off >>= 1) {
            if (t < off) red[t] += red[t + off];
            __syncthreads();
        }
        res[2 * k]     = m;
        res[2 * k + 1] = 1.0f / red[0];
        __syncthreads();
    }
    if (t == 0) {
        stats[b * 4 + 0] = res[0];
        stats[b * 4 + 1] = res[1];
        stats[b * 4 + 2] = res[2];
        stats[b * 4 + 3] = res[3];
    }
}

// ---------------------------------------------------------------------------
// Kernel 3: out[b,s,:] = wM[b,s,:] * alpha[b,s]
// One wave per (b,s); each lane recomputes alpha (cheap) and scales a float4.
// ---------------------------------------------------------------------------
__global__ __launch_bounds__(256) void scale_kernel(const float* __restrict__ wM,
                                                    const float* __restrict__ A1,
                                                    const float* __restrict__ A2,
                                                    const float* __restrict__ stats,
                                                    float* __restrict__ out) {
    const int wave = (int)((blockIdx.x * blockDim.x + threadIdx.x) >> 6);
    const int lane = threadIdx.x & 63;
    const int b = wave / SS;

    const float m1 = stats[b * 4 + 0];
    const float il1 = stats[b * 4 + 1];
    const float m2 = stats[b * 4 + 2];
    const float il2 = stats[b * 4 + 3];

    const float a1 = __expf(A1[wave] - m1) * il1;
    const float a2 = __expf(A2[wave] - m2) * il2;
    const float alpha = 0.5f * (a1 * a1 + a2 * a2);

    const size_t base = (size_t)wave * DD;
    const float4* in = reinterpret_cast<const float4*>(wM + base);
    float4* o = reinterpret_cast<float4*>(out + base);
    float4 v = in[lane];
    v.x *= alpha; v.y *= alpha; v.z *= alpha; v.w *= alpha;
    o[lane] = v;
}

extern "C" void kernel_launch(void* const* d_in, const int* in_sizes, int n_in,
                              void* d_out, int out_size, void* d_ws, size_t ws_size,
                              hipStream_t stream) {
    const float* wM = (const float*)d_in[0];
    const float* wd = (const float*)d_in[1];
    const float* e1 = (const float*)d_in[2];
    const float* e2 = (const float*)d_in[3];
    float* out = (float*)d_out;

    // Workspace layout: A1 [B*S], A2 [B*S], stats [B*4]
    float* A1 = (float*)d_ws;
    float* A2 = A1 + (size_t)BB * SS;
    float* stats = A2 + (size_t)BB * SS;

    const int waves = BB * SS;            // 131072 waves, 4 waves/block
    const int blocks = waves / 4;         // 32768

    dots_kernel<<<blocks, 256, 0, stream>>>(wd, e1, e2, A1, A2);
    stats_kernel<<<BB, 256, 0, stream>>>(A1, A2, stats);
    scale_kernel<<<blocks, 256, 0, stream>>>(wM, A1, A2, stats, out);
}

// Round 3
// 71.766 us; speedup vs baseline: 1.2703x; 1.2703x over previous
//
#include <hip/hip_runtime.h>

#define BB 32
#define SS 4096
#define DD 256
#define RD 8   // rows per wave in dots_kernel   (RD divides SS)
#define RS 4   // rows per wave in scale_kernel  (RS divides SS)

typedef float f4v __attribute__((ext_vector_type(4)));

// ---------------------------------------------------------------------------
// Kernel 1: A1[b,s] = dot(wd[b,s,:], e1[b,:]); A2 likewise.
// One wave per RD=8 rows; lane i handles float4 at d=4*i of each row.
// 8 independent 1KiB/wave loads in flight -> latency hidden.
// ---------------------------------------------------------------------------
__global__ __launch_bounds__(256) void dots_kernel(const float* __restrict__ wd,
                                                   const float* __restrict__ e1,
                                                   const float* __restrict__ e2,
                                                   float* __restrict__ A1,
                                                   float* __restrict__ A2) {
    const int wave = (int)((blockIdx.x * blockDim.x + threadIdx.x) >> 6);
    const int lane = threadIdx.x & 63;
    const int row0 = wave * RD;
    const int b = row0 >> 12;   // row0 / SS

    const f4v* e1v = reinterpret_cast<const f4v*>(e1 + b * DD);
    const f4v* e2v = reinterpret_cast<const f4v*>(e2 + b * DD);
    const f4v x1 = e1v[lane];
    const f4v x2 = e2v[lane];

    const f4v* wdv = reinterpret_cast<const f4v*>(wd) + (size_t)row0 * (DD / 4) + lane;
    f4v w[RD];
    #pragma unroll
    for (int r = 0; r < RD; ++r) w[r] = __builtin_nontemporal_load(&wdv[r * (DD / 4)]);

    float d1[RD], d2[RD];
    #pragma unroll
    for (int r = 0; r < RD; ++r) {
        d1[r] = w[r].x * x1.x + w[r].y * x1.y + w[r].z * x1.z + w[r].w * x1.w;
        d2[r] = w[r].x * x2.x + w[r].y * x2.y + w[r].z * x2.z + w[r].w * x2.w;
    }
    #pragma unroll
    for (int m = 32; m >= 1; m >>= 1) {
        #pragma unroll
        for (int r = 0; r < RD; ++r) {
            d1[r] += __shfl_xor(d1[r], m, 64);
            d2[r] += __shfl_xor(d2[r], m, 64);
        }
    }
    if (lane == 0) {
        #pragma unroll
        for (int r = 0; r < RD; ++r) {
            A1[row0 + r] = d1[r];
            A2[row0 + r] = d2[r];
        }
    }
}

// ---------------------------------------------------------------------------
// Kernel 2: softmax stats. One block per (b, k); k in {0,1} selects A1/A2.
// stats[b] = {m1, 1/l1, m2, 1/l2}
// ---------------------------------------------------------------------------
__global__ __launch_bounds__(256) void stats_kernel(const float* __restrict__ A1,
                                                    const float* __restrict__ A2,
                                                    float* __restrict__ stats) {
    const int b = blockIdx.x >> 1;
    const int k = blockIdx.x & 1;
    const int t = threadIdx.x;
    const float* __restrict__ A = (k ? A2 : A1) + (size_t)b * SS;
    __shared__ float red[256];

    // --- max ---
    float m = -3.0e38f;
    #pragma unroll
    for (int i = 0; i < SS / 256; ++i) m = fmaxf(m, A[t + i * 256]);
    red[t] = m;
    __syncthreads();
    #pragma unroll
    for (int off = 128; off >= 1; off >>= 1) {
        if (t < off) red[t] = fmaxf(red[t], red[t + off]);
        __syncthreads();
    }
    m = red[0];
    __syncthreads();

    // --- sum of exp ---
    float sum = 0.0f;
    #pragma unroll
    for (int i = 0; i < SS / 256; ++i) sum += __expf(A[t + i * 256] - m);
    red[t] = sum;
    __syncthreads();
    #pragma unroll
    for (int off = 128; off >= 1; off >>= 1) {
        if (t < off) red[t] += red[t + off];
        __syncthreads();
    }
    if (t == 0) {
        stats[b * 4 + 2 * k]     = m;
        stats[b * 4 + 2 * k + 1] = 1.0f / red[0];
    }
}

// ---------------------------------------------------------------------------
// Kernel 3: out[b,s,:] = wM[b,s,:] * alpha[b,s]
// One wave per RS=4 rows; alpha recomputed per lane (A rows are L2-hot).
// ---------------------------------------------------------------------------
__global__ __launch_bounds__(256) void scale_kernel(const float* __restrict__ wM,
                                                    const float* __restrict__ A1,
                                                    const float* __restrict__ A2,
                                                    const float* __restrict__ stats,
                                                    float* __restrict__ out) {
    const int wave = (int)((blockIdx.x * blockDim.x + threadIdx.x) >> 6);
    const int lane = threadIdx.x & 63;
    const int row0 = wave * RS;
    const int b = row0 >> 12;   // row0 / SS

    const float m1  = stats[b * 4 + 0];
    const float il1 = stats[b * 4 + 1];
    const float m2  = stats[b * 4 + 2];
    const float il2 = stats[b * 4 + 3];

    // Issue the big streaming loads first (independent).
    const f4v* in = reinterpret_cast<const f4v*>(wM) + (size_t)row0 * (DD / 4) + lane;
    f4v* o = reinterpret_cast<f4v*>(out) + (size_t)row0 * (DD / 4) + lane;
    f4v v[RS];
    #pragma unroll
    for (int r = 0; r < RS; ++r) v[r] = __builtin_nontemporal_load(&in[r * (DD / 4)]);

    float alpha[RS];
    #pragma unroll
    for (int r = 0; r < RS; ++r) {
        const float a1 = __expf(A1[row0 + r] - m1) * il1;
        const float a2 = __expf(A2[row0 + r] - m2) * il2;
        alpha[r] = 0.5f * (a1 * a1 + a2 * a2);
    }

    #pragma unroll
    for (int r = 0; r < RS; ++r) {
        f4v vv = v[r];
        vv.x *= alpha[r]; vv.y *= alpha[r]; vv.z *= alpha[r]; vv.w *= alpha[r];
        __builtin_nontemporal_store(vv, &o[r * (DD / 4)]);
    }
}

extern "C" void kernel_launch(void* const* d_in, const int* in_sizes, int n_in,
                              void* d_out, int out_size, void* d_ws, size_t ws_size,
                              hipStream_t stream) {
    const float* wM = (const float*)d_in[0];
    const float* wd = (const float*)d_in[1];
    const float* e1 = (const float*)d_in[2];
    const float* e2 = (const float*)d_in[3];
    float* out = (float*)d_out;

    // Workspace layout: A1 [B*S], A2 [B*S], stats [B*4]
    float* A1 = (float*)d_ws;
    float* A2 = A1 + (size_t)BB * SS;
    float* stats = A2 + (size_t)BB * SS;

    const int rows = BB * SS;                       // 131072
    dots_kernel<<<rows / (4 * RD), 256, 0, stream>>>(wd, e1, e2, A1, A2);
    stats_kernel<<<BB * 2, 256, 0, stream>>>(A1, A2, stats);
    scale_kernel<<<rows / (4 * RS), 256, 0, stream>>>(wM, A1, A2, stats, out);
}